// Round 3
// baseline (972.580 us; speedup 1.0000x reference)
//
#include <hip/hip_runtime.h>

#define N_NODES 100000
#define N_EDGES 1600000
#define IN_F    64
#define OUT_F   100

// ---- main-path workspace layout (bytes) ----
#define OFF_DEG   0                      // int[N_NODES]            -> 400000
#define OFF_OFFS  400000                 // int[N_NODES]            -> 800000
#define OFF_BSUM  800000                 // int[512]                -> 802048
#define OFF_HIST  802048                 // int[8][N_NODES] (3.2MB) -> 4002048
#define OFF_EIDS  4002048                // int[N_EDGES]  (6.4MB)   -> 10402048
#define WS_NEEDED 10402048

// ---- fallback layout (round-2, <8MB) ----
#define FB_DEG     0
#define FB_OFFS    524288
#define FB_CURSOR  1048576
#define FB_GCUR    1572864
#define FB_EIDS    1573888

#define SCAN_TPB      256
#define NODES_PER_BLK 1024
#define NBLK_SCAN     ((N_NODES + NODES_PER_BLK - 1) / NODES_PER_BLK)   // 98
#define EDGE_BLKS     ((N_EDGES / 4 + 255) / 256)                       // 1563

// ================= main path: 8-way privatized hist/cursor =================

// copy index = blockIdx.x & 7 (deterministic: hist & scatter use identical
// grids, so per-copy counts match per-copy increments exactly).
__global__ void k_hist8(const int* __restrict__ dst, int* __restrict__ hist) {
    int* h = hist + (blockIdx.x & 7) * N_NODES;
    int i = (blockIdx.x * blockDim.x + threadIdx.x) * 4;
    if (i + 3 < N_EDGES) {
        int4 d = *(const int4*)(dst + i);
        atomicAdd(&h[d.x], 1);
        atomicAdd(&h[d.y], 1);
        atomicAdd(&h[d.z], 1);
        atomicAdd(&h[d.w], 1);
    } else {
        for (int k = i; k < N_EDGES; k++) atomicAdd(&h[dst[k]], 1);
    }
}

// deg[n] = sum over 8 copies; bsum[b] = block total (for the global scan).
__global__ void kA_deg(const int* __restrict__ hist, int* __restrict__ deg,
                       int* __restrict__ bsum) {
    __shared__ int lds[SCAN_TPB / 64];
    int tid = threadIdx.x;
    int base = blockIdx.x * NODES_PER_BLK;
    int tot = 0;
    for (int k = 0; k < 4; k++) {
        int n = base + k * SCAN_TPB + tid;
        if (n < N_NODES) {
            int d = 0;
            #pragma unroll
            for (int x = 0; x < 8; x++) d += hist[x * N_NODES + n];
            deg[n] = d;
            tot += d;
        }
    }
    #pragma unroll
    for (int off = 32; off; off >>= 1) tot += __shfl_down(tot, off, 64);
    int lane = tid & 63, w = tid >> 6;
    if (lane == 0) lds[w] = tot;
    __syncthreads();
    if (tid == 0) {
        int s = 0;
        for (int i = 0; i < SCAN_TPB / 64; i++) s += lds[i];
        bsum[blockIdx.x] = s;
    }
}

// exclusive scan of bsum[0..NBLK_SCAN) in place; 1 block of 64 threads.
__global__ void kB_scan(int* __restrict__ bsum) {
    int lane = threadIdx.x;
    int carry = 0;
    for (int basei = 0; basei < NBLK_SCAN; basei += 64) {
        int idx = basei + lane;
        int v = (idx < NBLK_SCAN) ? bsum[idx] : 0;
        int x = v;
        #pragma unroll
        for (int off = 1; off < 64; off <<= 1) {
            int y = __shfl_up(x, off, 64);
            if (lane >= off) x += y;
        }
        int tot = __shfl(x, 63, 64);
        if (idx < NBLK_SCAN) bsum[idx] = carry + x - v;
        carry += tot;
    }
}

// per-block scan -> offs[n]; transform hist copies in place into per-copy
// starting cursors (offs[n] + prefix over copies). Node->range assignment is
// arbitrary-but-disjoint, which is all the gather needs.
__global__ void kC_offs(const int* __restrict__ deg, const int* __restrict__ bsum,
                        int* __restrict__ offs, int* __restrict__ hist) {
    __shared__ int wsum[SCAN_TPB / 64];
    int tid = threadIdx.x, lane = tid & 63, w = tid >> 6;
    int base = blockIdx.x * NODES_PER_BLK;
    int v[4];
    int ttot = 0;
    #pragma unroll
    for (int k = 0; k < 4; k++) {
        int n = base + k * SCAN_TPB + tid;
        v[k] = (n < N_NODES) ? deg[n] : 0;
        ttot += v[k];
    }
    int x = ttot;
    #pragma unroll
    for (int off = 1; off < 64; off <<= 1) {
        int y = __shfl_up(x, off, 64);
        if (lane >= off) x += y;
    }
    if (lane == 63) wsum[w] = x;
    __syncthreads();
    int wbase = 0;
    for (int i = 0; i < w; i++) wbase += wsum[i];
    int run = bsum[blockIdx.x] + wbase + (x - ttot);
    #pragma unroll
    for (int k = 0; k < 4; k++) {
        int n = base + k * SCAN_TPB + tid;
        if (n < N_NODES) {
            offs[n] = run;
            int r2 = run;
            #pragma unroll
            for (int xx = 0; xx < 8; xx++) {
                int t = hist[xx * N_NODES + n];
                hist[xx * N_NODES + n] = r2;
                r2 += t;
            }
            run += v[k];
        }
    }
}

__global__ void k_scatter8(const int* __restrict__ dst, int* __restrict__ cur,
                           int* __restrict__ eids) {
    int* c = cur + (blockIdx.x & 7) * N_NODES;
    int i = (blockIdx.x * blockDim.x + threadIdx.x) * 4;
    if (i + 3 < N_EDGES) {
        int4 d = *(const int4*)(dst + i);
        int p0 = atomicAdd(&c[d.x], 1);
        int p1 = atomicAdd(&c[d.y], 1);
        int p2 = atomicAdd(&c[d.z], 1);
        int p3 = atomicAdd(&c[d.w], 1);
        eids[p0] = i;
        eids[p1] = i + 1;
        eids[p2] = i + 2;
        eids[p3] = i + 3;
    } else {
        for (int k = i; k < N_EDGES; k++) {
            int pos = atomicAdd(&c[dst[k]], 1);
            eids[pos] = k;
        }
    }
}

// ================= fallback path (single-copy, round-2 style) =================

__global__ void fb_hist(const int* __restrict__ dst, int* __restrict__ deg) {
    int i = (blockIdx.x * blockDim.x + threadIdx.x) * 4;
    if (i + 3 < N_EDGES) {
        int4 d = *(const int4*)(dst + i);
        atomicAdd(&deg[d.x], 1); atomicAdd(&deg[d.y], 1);
        atomicAdd(&deg[d.z], 1); atomicAdd(&deg[d.w], 1);
    } else {
        for (int k = i; k < N_EDGES; k++) atomicAdd(&deg[dst[k]], 1);
    }
}

__global__ void fb_scan(const int* __restrict__ deg, int* __restrict__ offs,
                        int* __restrict__ cursor, int* __restrict__ gcur) {
    int n = blockIdx.x * blockDim.x + threadIdx.x;
    int lane = threadIdx.x & 63;
    int d = (n < N_NODES) ? deg[n] : 0;
    int x = d;
    #pragma unroll
    for (int off = 1; off < 64; off <<= 1) {
        int y = __shfl_up(x, off, 64);
        if (lane >= off) x += y;
    }
    int excl = x - d;
    int total = __shfl(x, 63, 64);
    int base = 0;
    if (lane == 63) base = atomicAdd(gcur, total);
    base = __shfl(base, 63, 64);
    if (n < N_NODES) {
        offs[n] = base + excl;
        cursor[n] = base + excl;
    }
}

__global__ void fb_scatter(const int* __restrict__ dst, int* __restrict__ cursor,
                           int* __restrict__ eids) {
    int i = (blockIdx.x * blockDim.x + threadIdx.x) * 4;
    if (i + 3 < N_EDGES) {
        int4 d = *(const int4*)(dst + i);
        int p0 = atomicAdd(&cursor[d.x], 1);
        int p1 = atomicAdd(&cursor[d.y], 1);
        int p2 = atomicAdd(&cursor[d.z], 1);
        int p3 = atomicAdd(&cursor[d.w], 1);
        eids[p0] = i; eids[p1] = i + 1; eids[p2] = i + 2; eids[p3] = i + 3;
    } else {
        for (int k = i; k < N_EDGES; k++) {
            int pos = atomicAdd(&cursor[dst[k]], 1);
            eids[pos] = k;
        }
    }
}

// ================= gather v3: chase-free =================
// One coalesced wave-load grabs ALL of a node's edge ids into lane registers
// (deg~Poisson(16), so c<=64 essentially always; slow fallback for c>64).
// E-row addresses come from readlane (SALU) -> 8 row loads in flight per wave
// with no memory dependency between them.
__global__ void __launch_bounds__(256) k_gather(
        const float* __restrict__ e, const int* __restrict__ eids,
        const int* __restrict__ offs, const int* __restrict__ deg,
        const float* __restrict__ W, const float* __restrict__ b,
        float* __restrict__ out, int n_waves_total) {
    int lane = threadIdx.x & 63;
    int wid  = (blockIdx.x * blockDim.x + threadIdx.x) >> 6;

    int row1 = 64 + lane;
    if (row1 >= OUT_F) row1 = 0;   // lanes 36..63 second output masked at store

    float w0[IN_F], w1[IN_F];
    const float4* W4 = (const float4*)W;
    #pragma unroll
    for (int j = 0; j < IN_F / 4; j++) {
        float4 t0 = W4[lane * (IN_F / 4) + j];
        w0[4*j+0] = t0.x; w0[4*j+1] = t0.y; w0[4*j+2] = t0.z; w0[4*j+3] = t0.w;
        float4 t1 = W4[row1 * (IN_F / 4) + j];
        w1[4*j+0] = t1.x; w1[4*j+1] = t1.y; w1[4*j+2] = t1.z; w1[4*j+3] = t1.w;
    }
    float bb0 = b[lane];
    float bb1 = b[row1];

    for (int n = wid; n < N_NODES; n += n_waves_total) {
        int o = __builtin_amdgcn_readfirstlane(offs[n]);
        int c = __builtin_amdgcn_readfirstlane(deg[n]);
        int cc = (c < 64) ? c : 64;

        int myeid = 0;
        if (lane < cc) myeid = eids[o + lane];

        float s0=0.f,s1=0.f,s2=0.f,s3=0.f,s4=0.f,s5=0.f,s6=0.f,s7=0.f;
        int j = 0;
        for (; j + 8 <= cc; j += 8) {
            int i0 = __builtin_amdgcn_readlane(myeid, j + 0);
            int i1 = __builtin_amdgcn_readlane(myeid, j + 1);
            int i2 = __builtin_amdgcn_readlane(myeid, j + 2);
            int i3 = __builtin_amdgcn_readlane(myeid, j + 3);
            int i4 = __builtin_amdgcn_readlane(myeid, j + 4);
            int i5 = __builtin_amdgcn_readlane(myeid, j + 5);
            int i6 = __builtin_amdgcn_readlane(myeid, j + 6);
            int i7 = __builtin_amdgcn_readlane(myeid, j + 7);
            s0 += e[((size_t)i0 << 6) + lane];
            s1 += e[((size_t)i1 << 6) + lane];
            s2 += e[((size_t)i2 << 6) + lane];
            s3 += e[((size_t)i3 << 6) + lane];
            s4 += e[((size_t)i4 << 6) + lane];
            s5 += e[((size_t)i5 << 6) + lane];
            s6 += e[((size_t)i6 << 6) + lane];
            s7 += e[((size_t)i7 << 6) + lane];
        }
        for (; j < cc; j++) {
            int i0 = __builtin_amdgcn_readlane(myeid, j);
            s0 += e[((size_t)i0 << 6) + lane];
        }
        for (int jj = 64; jj < c; jj++) {          // essentially never taken
            int id = eids[o + jj];
            s1 += e[((size_t)id << 6) + lane];
        }
        float s = ((s0 + s1) + (s2 + s3)) + ((s4 + s5) + (s6 + s7));

        float a0 = 0.f, a1 = 0.f;
        #pragma unroll
        for (int i = 0; i < IN_F; i++) {
            float si = __shfl(s, i, 64);   // constant-lane broadcast
            a0 = fmaf(si, w0[i], a0);
            a1 = fmaf(si, w1[i], a1);
        }

        float r  = (c > 0) ? (1.0f / (float)c) : 0.0f;
        float h0 = a0 * r + ((c > 0) ? bb0 : 0.0f);
        float h1 = a1 * r + ((c > 0) ? bb1 : 0.0f);

        size_t ob = (size_t)n * OUT_F;
        out[ob + lane] = h0;
        if (lane < OUT_F - 64) out[ob + 64 + lane] = h1;
    }
}

extern "C" void kernel_launch(void* const* d_in, const int* in_sizes, int n_in,
                              void* d_out, int out_size, void* d_ws, size_t ws_size,
                              hipStream_t stream) {
    const float* e   = (const float*)d_in[0];
    const int*   dst = (const int*)d_in[1];
    const float* W   = (const float*)d_in[2];
    const float* b   = (const float*)d_in[3];
    float* out = (float*)d_out;
    char* ws = (char*)d_ws;

    const int gblocks = 8192;
    const int n_waves = gblocks * 256 / 64;

    if (ws_size >= (size_t)WS_NEEDED) {
        int* deg  = (int*)(ws + OFF_DEG);
        int* offs = (int*)(ws + OFF_OFFS);
        int* bsum = (int*)(ws + OFF_BSUM);
        int* hist = (int*)(ws + OFF_HIST);
        int* eids = (int*)(ws + OFF_EIDS);

        hipMemsetAsync(hist, 0, 8 * N_NODES * sizeof(int), stream);
        k_hist8   <<<EDGE_BLKS, 256, 0, stream>>>(dst, hist);
        kA_deg    <<<NBLK_SCAN, SCAN_TPB, 0, stream>>>(hist, deg, bsum);
        kB_scan   <<<1, 64, 0, stream>>>(bsum);
        kC_offs   <<<NBLK_SCAN, SCAN_TPB, 0, stream>>>(deg, bsum, offs, hist);
        k_scatter8<<<EDGE_BLKS, 256, 0, stream>>>(dst, hist, eids);
        k_gather  <<<gblocks, 256, 0, stream>>>(e, eids, offs, deg, W, b, out, n_waves);
    } else {
        int* deg    = (int*)(ws + FB_DEG);
        int* offs   = (int*)(ws + FB_OFFS);
        int* cursor = (int*)(ws + FB_CURSOR);
        int* gcur   = (int*)(ws + FB_GCUR);
        int* eids   = (int*)(ws + FB_EIDS);

        hipMemsetAsync(deg, 0, N_NODES * sizeof(int), stream);
        hipMemsetAsync(gcur, 0, sizeof(int), stream);
        fb_hist   <<<EDGE_BLKS, 256, 0, stream>>>(dst, deg);
        fb_scan   <<<(N_NODES + 255) / 256, 256, 0, stream>>>(deg, offs, cursor, gcur);
        fb_scatter<<<EDGE_BLKS, 256, 0, stream>>>(dst, cursor, eids);
        k_gather  <<<gblocks, 256, 0, stream>>>(e, eids, offs, deg, W, b, out, n_waves);
    }
}

// Round 4
// 874.349 us; speedup vs baseline: 1.1123x; 1.1123x over previous
//
#include <hip/hip_runtime.h>

#define N_NODES 100000
#define N_EDGES 1600000
#define IN_F    64
#define OUT_F   100

#define K_BUCKETS 1563            // bucket = dst >> 6  (64 nodes per bucket)
#define NBLK      500             // edge-pass blocks
#define EPB       3200            // edges per block (exact: 500*3200 = 1.6M)
#define SCAN_LEN  (K_BUCKETS * NBLK)            // 781500
#define SCH       2048            // elements per scan block
#define SB        ((SCAN_LEN + SCH - 1) / SCH)  // 382
#define CAP       3072            // LDS sorted-list capacity (avg 1024, +64 sigma)

// ---- main-path workspace layout (bytes) ----
#define OFF_CNT   0                         // int[SCAN_LEN]  (3.126 MB)
#define OFF_PART  (SCAN_LEN * 4)            // int[SB]
#define OFF_BIN   (SCAN_LEN * 4 + 2048)     // int[N_EDGES]   (6.4 MB)
#define WS_NEEDED (OFF_BIN + N_EDGES * 4)   // 9,528,048

// ---- fallback layout (atomic path, < 8 MB) ----
#define FB_DEG     0
#define FB_OFFS    524288
#define FB_CURSOR  1048576
#define FB_GCUR    1572864
#define FB_EIDS    1573888

// ===================== pass A: per-block bucket histogram =====================
__global__ void __launch_bounds__(256) k_count(const int* __restrict__ dst,
                                               int* __restrict__ cnt) {
    __shared__ int h[K_BUCKETS];
    for (int i = threadIdx.x; i < K_BUCKETS; i += 256) h[i] = 0;
    __syncthreads();
    int base = blockIdx.x * EPB;
    #pragma unroll
    for (int it = 0; it < 3; it++) {
        int i = base + it * 1024 + threadIdx.x * 4;
        int4 d = *(const int4*)(dst + i);
        atomicAdd(&h[d.x >> 6], 1);
        atomicAdd(&h[d.y >> 6], 1);
        atomicAdd(&h[d.z >> 6], 1);
        atomicAdd(&h[d.w >> 6], 1);
    }
    if (threadIdx.x < 128) {
        int i = base + 3072 + threadIdx.x;
        atomicAdd(&h[dst[i] >> 6], 1);
    }
    __syncthreads();
    for (int k = threadIdx.x; k < K_BUCKETS; k += 256)
        cnt[k * NBLK + blockIdx.x] = h[k];
}

// ===================== pass B: flat exclusive scan of cnt =====================
__global__ void k_s1(const int* __restrict__ cnt, int* __restrict__ part) {
    __shared__ int ws_[4];
    int b0 = blockIdx.x * SCH;
    int t = threadIdx.x;
    int tot = 0;
    #pragma unroll
    for (int i = 0; i < 8; i++) {
        int idx = b0 + i * 256 + t;
        if (idx < SCAN_LEN) tot += cnt[idx];
    }
    #pragma unroll
    for (int off = 32; off; off >>= 1) tot += __shfl_down(tot, off, 64);
    if ((t & 63) == 0) ws_[t >> 6] = tot;
    __syncthreads();
    if (t == 0) part[blockIdx.x] = ws_[0] + ws_[1] + ws_[2] + ws_[3];
}

__global__ void k_s2(int* __restrict__ part) {
    int lane = threadIdx.x;
    int carry = 0;
    for (int b0 = 0; b0 < SB; b0 += 64) {
        int idx = b0 + lane;
        int v = (idx < SB) ? part[idx] : 0;
        int x = v;
        #pragma unroll
        for (int off = 1; off < 64; off <<= 1) {
            int y = __shfl_up(x, off, 64);
            if (lane >= off) x += y;
        }
        int tot = __shfl(x, 63, 64);
        if (idx < SB) part[idx] = carry + x - v;
        carry += tot;
    }
}

__global__ void k_s3(int* __restrict__ cnt, const int* __restrict__ part) {
    __shared__ int wsum[4];
    int t = threadIdx.x, lane = t & 63, w = t >> 6;
    int idx0 = blockIdx.x * SCH + t * 8;
    int v[8];
    int s = 0;
    #pragma unroll
    for (int i = 0; i < 8; i++) {
        v[i] = (idx0 + i < SCAN_LEN) ? cnt[idx0 + i] : 0;
        s += v[i];
    }
    int x = s;
    #pragma unroll
    for (int off = 1; off < 64; off <<= 1) {
        int y = __shfl_up(x, off, 64);
        if (lane >= off) x += y;
    }
    if (lane == 63) wsum[w] = x;
    __syncthreads();
    int wb = 0;
    for (int i = 0; i < w; i++) wb += wsum[i];
    int run = part[blockIdx.x] + wb + (x - s);
    #pragma unroll
    for (int i = 0; i < 8; i++) {
        int tmp = v[i];
        if (idx0 + i < SCAN_LEN) cnt[idx0 + i] = run;
        run += tmp;
    }
}

// ===================== pass C: bin edges (LDS cursors only) =====================
__global__ void __launch_bounds__(256) k_bin(const int* __restrict__ dst,
                                             const int* __restrict__ scn,
                                             int* __restrict__ binned) {
    __shared__ int cur[K_BUCKETS];
    for (int k = threadIdx.x; k < K_BUCKETS; k += 256)
        cur[k] = scn[k * NBLK + blockIdx.x];
    __syncthreads();
    int base = blockIdx.x * EPB;
    #pragma unroll
    for (int it = 0; it < 3; it++) {
        int i = base + it * 1024 + threadIdx.x * 4;
        int4 d = *(const int4*)(dst + i);
        int p;
        p = atomicAdd(&cur[d.x >> 6], 1); binned[p] = ((d.x & 63) << 21) | i;
        p = atomicAdd(&cur[d.y >> 6], 1); binned[p] = ((d.y & 63) << 21) | (i + 1);
        p = atomicAdd(&cur[d.z >> 6], 1); binned[p] = ((d.z & 63) << 21) | (i + 2);
        p = atomicAdd(&cur[d.w >> 6], 1); binned[p] = ((d.w & 63) << 21) | (i + 3);
    }
    if (threadIdx.x < 128) {
        int i = base + 3072 + threadIdx.x;
        int d = dst[i];
        int p = atomicAdd(&cur[d >> 6], 1);
        binned[p] = ((d & 63) << 21) | i;
    }
}

// ===================== fused: sort-in-LDS + gather-sum + GEMV =====================
// One block per bucket (64 nodes). Counting-sort the bucket's edges by local
// node id in LDS, then each wave gathers e-rows for 16 nodes (lane = feature,
// register accumulate), scales by 1/deg, round-trips the mean row through LDS
// (16 independent ds_read_b128 broadcasts -- NOT 64 serialized bpermutes), and
// does the 100-output GEMV against W rows held in 128 VGPRs.
__global__ void __launch_bounds__(256) k_fused(
        const float* __restrict__ e, const int* __restrict__ binned,
        const int* __restrict__ scn, const float* __restrict__ W,
        const float* __restrict__ b, float* __restrict__ out) {
    __shared__ int   deg[64];
    __shared__ int   lofs[64];
    __shared__ int   sorted[CAP];
    __shared__ float srow[4][64];

    int tid = threadIdx.x, lane = tid & 63, w = tid >> 6;
    int bk = blockIdx.x;
    int base = scn[bk * NBLK];
    int end  = (bk + 1 < K_BUCKETS) ? scn[(bk + 1) * NBLK] : N_EDGES;
    int cntb = end - base;

    for (int i = tid; i < 64; i += 256) deg[i] = 0;
    __syncthreads();

    bool fast = (cntb <= CAP);
    if (fast) {
        int pk[12], rk[12];
        int nI = (cntb + 255) >> 8;
        for (int i = 0; i < nI; i++) {
            int idx = tid + i * 256;
            if (idx < cntb) {
                int p = binned[base + idx];
                pk[i] = p;
                rk[i] = atomicAdd(&deg[p >> 21], 1);
            } else pk[i] = -1;
        }
        __syncthreads();
        if (w == 0) {
            int d = deg[lane];
            int x = d;
            #pragma unroll
            for (int off = 1; off < 64; off <<= 1) {
                int y = __shfl_up(x, off, 64);
                if (lane >= off) x += y;
            }
            lofs[lane] = x - d;
        }
        __syncthreads();
        for (int i = 0; i < nI; i++) {
            if (pk[i] >= 0) {
                int lid = pk[i] >> 21;
                sorted[lofs[lid] + rk[i]] = pk[i] & 0x1FFFFF;
            }
        }
        __syncthreads();
    }

    // W rows into registers (loaded after sort phase to limit live pressure)
    int row1 = 64 + lane;
    if (row1 >= OUT_F) row1 = 0;
    float w0[IN_F], w1[IN_F];
    const float4* W4 = (const float4*)W;
    #pragma unroll
    for (int j = 0; j < IN_F / 4; j++) {
        float4 t0 = W4[lane * (IN_F / 4) + j];
        w0[4*j+0] = t0.x; w0[4*j+1] = t0.y; w0[4*j+2] = t0.z; w0[4*j+3] = t0.w;
        float4 t1 = W4[row1 * (IN_F / 4) + j];
        w1[4*j+0] = t1.x; w1[4*j+1] = t1.y; w1[4*j+2] = t1.z; w1[4*j+3] = t1.w;
    }
    float bb0 = b[lane];
    float bb1 = b[row1];

    for (int t = 0; t < 16; t++) {
        int lid = w * 16 + t;
        int node = bk * 64 + lid;
        if (node >= N_NODES) break;          // only last (32-node) bucket

        float s0=0.f,s1=0.f,s2=0.f,s3=0.f,s4=0.f,s5=0.f,s6=0.f,s7=0.f;
        int c;
        if (fast) {
            int o = lofs[lid];
            c = deg[lid];
            for (int cb = 0; cb < c; cb += 64) {
                int cc = c - cb; if (cc > 64) cc = 64;
                int myeid = 0;
                if (lane < cc) myeid = sorted[o + cb + lane];
                int j = 0;
                for (; j + 8 <= cc; j += 8) {
                    int i0 = __builtin_amdgcn_readlane(myeid, j + 0);
                    int i1 = __builtin_amdgcn_readlane(myeid, j + 1);
                    int i2 = __builtin_amdgcn_readlane(myeid, j + 2);
                    int i3 = __builtin_amdgcn_readlane(myeid, j + 3);
                    int i4 = __builtin_amdgcn_readlane(myeid, j + 4);
                    int i5 = __builtin_amdgcn_readlane(myeid, j + 5);
                    int i6 = __builtin_amdgcn_readlane(myeid, j + 6);
                    int i7 = __builtin_amdgcn_readlane(myeid, j + 7);
                    s0 += e[((size_t)i0 << 6) + lane];
                    s1 += e[((size_t)i1 << 6) + lane];
                    s2 += e[((size_t)i2 << 6) + lane];
                    s3 += e[((size_t)i3 << 6) + lane];
                    s4 += e[((size_t)i4 << 6) + lane];
                    s5 += e[((size_t)i5 << 6) + lane];
                    s6 += e[((size_t)i6 << 6) + lane];
                    s7 += e[((size_t)i7 << 6) + lane];
                }
                for (; j < cc; j++) {
                    int i0 = __builtin_amdgcn_readlane(myeid, j);
                    s0 += e[((size_t)i0 << 6) + lane];
                }
            }
        } else {
            // correctness-only path for pathological bucket overflow
            c = 0;
            for (int j0 = 0; j0 < cntb; j0 += 64) {
                int idx = j0 + lane;
                int p = (idx < cntb) ? binned[base + idx] : -1;
                bool m = (p >= 0) && ((p >> 21) == lid);
                unsigned long long msk = __ballot(m);
                c += __popcll(msk);
                while (msk) {
                    int l = __ffsll((long long)msk) - 1;
                    msk &= msk - 1;
                    int eid = __builtin_amdgcn_readlane(p, l) & 0x1FFFFF;
                    s0 += e[((size_t)eid << 6) + lane];
                }
            }
        }
        float s = ((s0 + s1) + (s2 + s3)) + ((s4 + s5) + (s6 + s7));
        float inv = (c > 0) ? 1.0f / (float)c : 0.0f;

        // GEMV: LDS round trip, 16 independent b128 broadcast reads
        float* sr = &srow[w][0];
        sr[lane] = s * inv;
        float a0 = 0.f, a1 = 0.f;
        const float4* sr4 = (const float4*)sr;
        #pragma unroll
        for (int q = 0; q < 16; q++) {
            float4 f = sr4[q];
            a0 = fmaf(f.x, w0[4*q+0], a0);  a1 = fmaf(f.x, w1[4*q+0], a1);
            a0 = fmaf(f.y, w0[4*q+1], a0);  a1 = fmaf(f.y, w1[4*q+1], a1);
            a0 = fmaf(f.z, w0[4*q+2], a0);  a1 = fmaf(f.z, w1[4*q+2], a1);
            a0 = fmaf(f.w, w0[4*q+3], a0);  a1 = fmaf(f.w, w1[4*q+3], a1);
        }
        float h0 = (c > 0) ? a0 + bb0 : 0.0f;
        float h1 = (c > 0) ? a1 + bb1 : 0.0f;

        size_t ob = (size_t)node * OUT_F;
        out[ob + lane] = h0;
        if (lane < OUT_F - 64) out[ob + 64 + lane] = h1;
    }
}

// ===================== fallback path (atomic-based, round-3) =====================
__global__ void fb_hist(const int* __restrict__ dst, int* __restrict__ deg) {
    int i = (blockIdx.x * blockDim.x + threadIdx.x) * 4;
    if (i + 3 < N_EDGES) {
        int4 d = *(const int4*)(dst + i);
        atomicAdd(&deg[d.x], 1); atomicAdd(&deg[d.y], 1);
        atomicAdd(&deg[d.z], 1); atomicAdd(&deg[d.w], 1);
    } else {
        for (int k = i; k < N_EDGES; k++) atomicAdd(&deg[dst[k]], 1);
    }
}

__global__ void fb_scan(const int* __restrict__ deg, int* __restrict__ offs,
                        int* __restrict__ cursor, int* __restrict__ gcur) {
    int n = blockIdx.x * blockDim.x + threadIdx.x;
    int lane = threadIdx.x & 63;
    int d = (n < N_NODES) ? deg[n] : 0;
    int x = d;
    #pragma unroll
    for (int off = 1; off < 64; off <<= 1) {
        int y = __shfl_up(x, off, 64);
        if (lane >= off) x += y;
    }
    int excl = x - d;
    int total = __shfl(x, 63, 64);
    int bs = 0;
    if (lane == 63) bs = atomicAdd(gcur, total);
    bs = __shfl(bs, 63, 64);
    if (n < N_NODES) {
        offs[n] = bs + excl;
        cursor[n] = bs + excl;
    }
}

__global__ void fb_scatter(const int* __restrict__ dst, int* __restrict__ cursor,
                           int* __restrict__ eids) {
    int i = (blockIdx.x * blockDim.x + threadIdx.x) * 4;
    if (i + 3 < N_EDGES) {
        int4 d = *(const int4*)(dst + i);
        int p0 = atomicAdd(&cursor[d.x], 1);
        int p1 = atomicAdd(&cursor[d.y], 1);
        int p2 = atomicAdd(&cursor[d.z], 1);
        int p3 = atomicAdd(&cursor[d.w], 1);
        eids[p0] = i; eids[p1] = i + 1; eids[p2] = i + 2; eids[p3] = i + 3;
    } else {
        for (int k = i; k < N_EDGES; k++) {
            int pos = atomicAdd(&cursor[dst[k]], 1);
            eids[pos] = k;
        }
    }
}

__global__ void __launch_bounds__(256) fb_gather(
        const float* __restrict__ e, const int* __restrict__ eids,
        const int* __restrict__ offs, const int* __restrict__ deg,
        const float* __restrict__ W, const float* __restrict__ b,
        float* __restrict__ out, int n_waves_total) {
    __shared__ float srow[4][64];
    int lane = threadIdx.x & 63, w = (threadIdx.x >> 6) & 3;
    int wid  = (blockIdx.x * blockDim.x + threadIdx.x) >> 6;
    int row1 = 64 + lane;
    if (row1 >= OUT_F) row1 = 0;
    float w0[IN_F], w1[IN_F];
    const float4* W4 = (const float4*)W;
    #pragma unroll
    for (int j = 0; j < IN_F / 4; j++) {
        float4 t0 = W4[lane * (IN_F / 4) + j];
        w0[4*j+0] = t0.x; w0[4*j+1] = t0.y; w0[4*j+2] = t0.z; w0[4*j+3] = t0.w;
        float4 t1 = W4[row1 * (IN_F / 4) + j];
        w1[4*j+0] = t1.x; w1[4*j+1] = t1.y; w1[4*j+2] = t1.z; w1[4*j+3] = t1.w;
    }
    float bb0 = b[lane];
    float bb1 = b[row1];
    for (int n = wid; n < N_NODES; n += n_waves_total) {
        int o = __builtin_amdgcn_readfirstlane(offs[n]);
        int c = __builtin_amdgcn_readfirstlane(deg[n]);
        float s0 = 0.f, s1 = 0.f;
        for (int cb = 0; cb < c; cb += 64) {
            int cc = c - cb; if (cc > 64) cc = 64;
            int myeid = 0;
            if (lane < cc) myeid = eids[o + cb + lane];
            for (int j = 0; j < cc; j += 2) {
                int i0 = __builtin_amdgcn_readlane(myeid, j);
                s0 += e[((size_t)i0 << 6) + lane];
                if (j + 1 < cc) {
                    int i1 = __builtin_amdgcn_readlane(myeid, j + 1);
                    s1 += e[((size_t)i1 << 6) + lane];
                }
            }
        }
        float* sr = &srow[w][0];
        sr[lane] = (s0 + s1) * ((c > 0) ? 1.0f / (float)c : 0.0f);
        float a0 = 0.f, a1 = 0.f;
        const float4* sr4 = (const float4*)sr;
        #pragma unroll
        for (int q = 0; q < 16; q++) {
            float4 f = sr4[q];
            a0 = fmaf(f.x, w0[4*q+0], a0);  a1 = fmaf(f.x, w1[4*q+0], a1);
            a0 = fmaf(f.y, w0[4*q+1], a0);  a1 = fmaf(f.y, w1[4*q+1], a1);
            a0 = fmaf(f.z, w0[4*q+2], a0);  a1 = fmaf(f.z, w1[4*q+2], a1);
            a0 = fmaf(f.w, w0[4*q+3], a0);  a1 = fmaf(f.w, w1[4*q+3], a1);
        }
        float h0 = (c > 0) ? a0 + bb0 : 0.0f;
        float h1 = (c > 0) ? a1 + bb1 : 0.0f;
        size_t ob = (size_t)n * OUT_F;
        out[ob + lane] = h0;
        if (lane < OUT_F - 64) out[ob + 64 + lane] = h1;
    }
}

extern "C" void kernel_launch(void* const* d_in, const int* in_sizes, int n_in,
                              void* d_out, int out_size, void* d_ws, size_t ws_size,
                              hipStream_t stream) {
    const float* e   = (const float*)d_in[0];
    const int*   dst = (const int*)d_in[1];
    const float* W   = (const float*)d_in[2];
    const float* b   = (const float*)d_in[3];
    float* out = (float*)d_out;
    char* ws = (char*)d_ws;

    if (ws_size >= (size_t)WS_NEEDED) {
        int* cnt    = (int*)(ws + OFF_CNT);
        int* part   = (int*)(ws + OFF_PART);
        int* binned = (int*)(ws + OFF_BIN);

        k_count<<<NBLK, 256, 0, stream>>>(dst, cnt);
        k_s1   <<<SB, 256, 0, stream>>>(cnt, part);
        k_s2   <<<1, 64, 0, stream>>>(part);
        k_s3   <<<SB, 256, 0, stream>>>(cnt, part);
        k_bin  <<<NBLK, 256, 0, stream>>>(dst, cnt, binned);
        k_fused<<<K_BUCKETS, 256, 0, stream>>>(e, binned, cnt, W, b, out);
    } else {
        int* deg    = (int*)(ws + FB_DEG);
        int* offs   = (int*)(ws + FB_OFFS);
        int* cursor = (int*)(ws + FB_CURSOR);
        int* gcur   = (int*)(ws + FB_GCUR);
        int* eids   = (int*)(ws + FB_EIDS);

        hipMemsetAsync(deg, 0, N_NODES * sizeof(int), stream);
        hipMemsetAsync(gcur, 0, sizeof(int), stream);
        fb_hist   <<<(N_EDGES / 4 + 255) / 256, 256, 0, stream>>>(dst, deg);
        fb_scan   <<<(N_NODES + 255) / 256, 256, 0, stream>>>(deg, offs, cursor, gcur);
        fb_scatter<<<(N_EDGES / 4 + 255) / 256, 256, 0, stream>>>(dst, cursor, eids);
        fb_gather <<<8192, 256, 0, stream>>>(e, eids, offs, deg, W, b, out, 8192 * 4);
    }
}

// Round 5
// 649.016 us; speedup vs baseline: 1.4985x; 1.3472x over previous
//
#include <hip/hip_runtime.h>

#define N_NODES 100000
#define N_EDGES 1600000
#define IN_F    64
#define OUT_F   100

#define K_BUCKETS 1563            // bucket = dst >> 6  (64 nodes per bucket)
#define NBLK      500             // edge-pass blocks
#define EPB       3200            // edges per block (exact: 500*3200 = 1.6M)
#define SCAN_LEN  (K_BUCKETS * NBLK)            // 781500
#define SCH       2048            // elements per scan block
#define SB        ((SCAN_LEN + SCH - 1) / SCH)  // 382
#define CAP       3072            // LDS sorted-list capacity (avg 1024, +64 sigma)

// ---- main-path workspace layout (bytes) ----
#define OFF_CNT   0                         // int[SCAN_LEN]  (3.126 MB)
#define OFF_PART  (SCAN_LEN * 4)            // int[SB]
#define OFF_BIN   (SCAN_LEN * 4 + 2048)     // int[N_EDGES]   (6.4 MB)
#define WS_NEEDED (OFF_BIN + N_EDGES * 4)   // 9,528,048

// ---- fallback layout (atomic path, < 8 MB) ----
#define FB_DEG     0
#define FB_OFFS    524288
#define FB_CURSOR  1048576
#define FB_GCUR    1572864
#define FB_EIDS    1573888

// ===================== pass A: per-block bucket histogram =====================
__global__ void __launch_bounds__(256) k_count(const int* __restrict__ dst,
                                               int* __restrict__ cnt) {
    __shared__ int h[K_BUCKETS];
    for (int i = threadIdx.x; i < K_BUCKETS; i += 256) h[i] = 0;
    __syncthreads();
    int base = blockIdx.x * EPB;
    #pragma unroll
    for (int it = 0; it < 3; it++) {
        int i = base + it * 1024 + threadIdx.x * 4;
        int4 d = *(const int4*)(dst + i);
        atomicAdd(&h[d.x >> 6], 1);
        atomicAdd(&h[d.y >> 6], 1);
        atomicAdd(&h[d.z >> 6], 1);
        atomicAdd(&h[d.w >> 6], 1);
    }
    if (threadIdx.x < 128) {
        int i = base + 3072 + threadIdx.x;
        atomicAdd(&h[dst[i] >> 6], 1);
    }
    __syncthreads();
    for (int k = threadIdx.x; k < K_BUCKETS; k += 256)
        cnt[k * NBLK + blockIdx.x] = h[k];
}

// ===================== pass B: flat exclusive scan of cnt =====================
__global__ void k_s1(const int* __restrict__ cnt, int* __restrict__ part) {
    __shared__ int ws_[4];
    int b0 = blockIdx.x * SCH;
    int t = threadIdx.x;
    int tot = 0;
    #pragma unroll
    for (int i = 0; i < 8; i++) {
        int idx = b0 + i * 256 + t;
        if (idx < SCAN_LEN) tot += cnt[idx];
    }
    #pragma unroll
    for (int off = 32; off; off >>= 1) tot += __shfl_down(tot, off, 64);
    if ((t & 63) == 0) ws_[t >> 6] = tot;
    __syncthreads();
    if (t == 0) part[blockIdx.x] = ws_[0] + ws_[1] + ws_[2] + ws_[3];
}

__global__ void k_s2(int* __restrict__ part) {
    int lane = threadIdx.x;
    int carry = 0;
    for (int b0 = 0; b0 < SB; b0 += 64) {
        int idx = b0 + lane;
        int v = (idx < SB) ? part[idx] : 0;
        int x = v;
        #pragma unroll
        for (int off = 1; off < 64; off <<= 1) {
            int y = __shfl_up(x, off, 64);
            if (lane >= off) x += y;
        }
        int tot = __shfl(x, 63, 64);
        if (idx < SB) part[idx] = carry + x - v;
        carry += tot;
    }
}

__global__ void k_s3(int* __restrict__ cnt, const int* __restrict__ part) {
    __shared__ int wsum[4];
    int t = threadIdx.x, lane = t & 63, w = t >> 6;
    int idx0 = blockIdx.x * SCH + t * 8;
    int v[8];
    int s = 0;
    #pragma unroll
    for (int i = 0; i < 8; i++) {
        v[i] = (idx0 + i < SCAN_LEN) ? cnt[idx0 + i] : 0;
        s += v[i];
    }
    int x = s;
    #pragma unroll
    for (int off = 1; off < 64; off <<= 1) {
        int y = __shfl_up(x, off, 64);
        if (lane >= off) x += y;
    }
    if (lane == 63) wsum[w] = x;
    __syncthreads();
    int wb = 0;
    for (int i = 0; i < w; i++) wb += wsum[i];
    int run = part[blockIdx.x] + wb + (x - s);
    #pragma unroll
    for (int i = 0; i < 8; i++) {
        int tmp = v[i];
        if (idx0 + i < SCAN_LEN) cnt[idx0 + i] = run;
        run += tmp;
    }
}

// ===================== pass C: bin edges (LDS cursors only) =====================
__global__ void __launch_bounds__(256) k_bin(const int* __restrict__ dst,
                                             const int* __restrict__ scn,
                                             int* __restrict__ binned) {
    __shared__ int cur[K_BUCKETS];
    for (int k = threadIdx.x; k < K_BUCKETS; k += 256)
        cur[k] = scn[k * NBLK + blockIdx.x];
    __syncthreads();
    int base = blockIdx.x * EPB;
    #pragma unroll
    for (int it = 0; it < 3; it++) {
        int i = base + it * 1024 + threadIdx.x * 4;
        int4 d = *(const int4*)(dst + i);
        int p;
        p = atomicAdd(&cur[d.x >> 6], 1); binned[p] = ((d.x & 63) << 21) | i;
        p = atomicAdd(&cur[d.y >> 6], 1); binned[p] = ((d.y & 63) << 21) | (i + 1);
        p = atomicAdd(&cur[d.z >> 6], 1); binned[p] = ((d.z & 63) << 21) | (i + 2);
        p = atomicAdd(&cur[d.w >> 6], 1); binned[p] = ((d.w & 63) << 21) | (i + 3);
    }
    if (threadIdx.x < 128) {
        int i = base + 3072 + threadIdx.x;
        int d = dst[i];
        int p = atomicAdd(&cur[d >> 6], 1);
        binned[p] = ((d & 63) << 21) | i;
    }
}

// ===================== fused: sort-in-LDS + float4 gather + GEMV =====================
// One block per bucket (64 nodes). Counting-sort bucket's edges by local node
// id in LDS. Gather phase uses a float4-lane layout: lane = (group g=lane>>4,
// sub=lane&15); one wave-load covers FOUR edge rows (64 x 16B = 1KB), edge ids
// come per-lane from LDS `sorted` (group-broadcast ds_read_b32). 4 independent
// 1KB loads in flight per node, branchless masked-FMA tail. Cross-group
// reduce = 8 shfl_xor. GEMV against W in 128 VGPRs via 16 b128 LDS broadcasts.
__global__ void __launch_bounds__(256, 2) k_fused(
        const float* __restrict__ e, const int* __restrict__ binned,
        const int* __restrict__ scn, const float* __restrict__ W,
        const float* __restrict__ b, float* __restrict__ out) {
    __shared__ int   deg[64];
    __shared__ int   lofs[64];
    __shared__ int   sorted[CAP];
    __shared__ __align__(16) float srow[4][64];

    int tid = threadIdx.x, lane = tid & 63, w = tid >> 6;
    int sub = lane & 15, g = lane >> 4;
    int bk = blockIdx.x;
    int base = scn[bk * NBLK];
    int end  = (bk + 1 < K_BUCKETS) ? scn[(bk + 1) * NBLK] : N_EDGES;
    int cntb = end - base;

    for (int i = tid; i < 64; i += 256) deg[i] = 0;
    __syncthreads();

    bool fast = (cntb <= CAP);
    if (fast) {
        int pk[12], rk[12];
        int nI = (cntb + 255) >> 8;
        for (int i = 0; i < nI; i++) {
            int idx = tid + i * 256;
            if (idx < cntb) {
                int p = binned[base + idx];
                pk[i] = p;
                rk[i] = atomicAdd(&deg[p >> 21], 1);
            } else pk[i] = -1;
        }
        __syncthreads();
        if (w == 0) {
            int d = deg[lane];
            int x = d;
            #pragma unroll
            for (int off = 1; off < 64; off <<= 1) {
                int y = __shfl_up(x, off, 64);
                if (lane >= off) x += y;
            }
            lofs[lane] = x - d;
        }
        __syncthreads();
        for (int i = 0; i < nI; i++) {
            if (pk[i] >= 0) {
                int lid = pk[i] >> 21;
                sorted[lofs[lid] + rk[i]] = pk[i] & 0x1FFFFF;
            }
        }
        __syncthreads();
    }

    // W rows into registers
    int row1 = 64 + lane;
    if (row1 >= OUT_F) row1 = 0;
    float w0[IN_F], w1[IN_F];
    const float4* W4 = (const float4*)W;
    #pragma unroll
    for (int j = 0; j < IN_F / 4; j++) {
        float4 t0 = W4[lane * (IN_F / 4) + j];
        w0[4*j+0] = t0.x; w0[4*j+1] = t0.y; w0[4*j+2] = t0.z; w0[4*j+3] = t0.w;
        float4 t1 = W4[row1 * (IN_F / 4) + j];
        w1[4*j+0] = t1.x; w1[4*j+1] = t1.y; w1[4*j+2] = t1.z; w1[4*j+3] = t1.w;
    }
    float bb0 = b[lane];
    float bb1 = b[row1];

    const float4* e4 = (const float4*)e;

    for (int t = 0; t < 16; t++) {
        int lid = w * 16 + t;
        int node = bk * 64 + lid;
        if (node >= N_NODES) break;          // only last (32-node) bucket

        int c;
        float* sr = &srow[w][0];

        if (fast) {
            int o = lofs[lid];
            c = deg[lid];
            if (c > 0) {
                float4 a0 = {0,0,0,0}, a1 = {0,0,0,0}, a2 = {0,0,0,0}, a3 = {0,0,0,0};
                for (int cb = 0; cb < c; cb += 64) {
                    int cc = c - cb; if (cc > 64) cc = 64;
                    int ng = (cc + 3) >> 2;          // edge groups of 4
                    int ob = o + cb;
                    for (int i = 0; i < ng; i += 4) {
                        // 4 independent 1KB loads (4 edges each), branchless
                        int idx0 = (i + 0) * 4 + g;
                        int idx1 = (i + 1) * 4 + g;
                        int idx2 = (i + 2) * 4 + g;
                        int idx3 = (i + 3) * 4 + g;
                        int c1 = cc - 1;
                        int e0 = sorted[ob + ((idx0 < c1) ? idx0 : c1)];
                        int e1 = sorted[ob + ((idx1 < c1) ? idx1 : c1)];
                        int e2 = sorted[ob + ((idx2 < c1) ? idx2 : c1)];
                        int e3 = sorted[ob + ((idx3 < c1) ? idx3 : c1)];
                        float4 v0 = e4[(size_t)e0 * 16 + sub];
                        float4 v1 = e4[(size_t)e1 * 16 + sub];
                        float4 v2 = e4[(size_t)e2 * 16 + sub];
                        float4 v3 = e4[(size_t)e3 * 16 + sub];
                        float m0 = (idx0 < cc) ? 1.0f : 0.0f;
                        float m1 = (idx1 < cc) ? 1.0f : 0.0f;
                        float m2 = (idx2 < cc) ? 1.0f : 0.0f;
                        float m3 = (idx3 < cc) ? 1.0f : 0.0f;
                        a0.x = fmaf(v0.x, m0, a0.x); a0.y = fmaf(v0.y, m0, a0.y);
                        a0.z = fmaf(v0.z, m0, a0.z); a0.w = fmaf(v0.w, m0, a0.w);
                        a1.x = fmaf(v1.x, m1, a1.x); a1.y = fmaf(v1.y, m1, a1.y);
                        a1.z = fmaf(v1.z, m1, a1.z); a1.w = fmaf(v1.w, m1, a1.w);
                        a2.x = fmaf(v2.x, m2, a2.x); a2.y = fmaf(v2.y, m2, a2.y);
                        a2.z = fmaf(v2.z, m2, a2.z); a2.w = fmaf(v2.w, m2, a2.w);
                        a3.x = fmaf(v3.x, m3, a3.x); a3.y = fmaf(v3.y, m3, a3.y);
                        a3.z = fmaf(v3.z, m3, a3.z); a3.w = fmaf(v3.w, m3, a3.w);
                    }
                }
                float4 s;
                s.x = (a0.x + a1.x) + (a2.x + a3.x);
                s.y = (a0.y + a1.y) + (a2.y + a3.y);
                s.z = (a0.z + a1.z) + (a2.z + a3.z);
                s.w = (a0.w + a1.w) + (a2.w + a3.w);
                // reduce across the 4 lane-groups
                s.x += __shfl_xor(s.x, 16, 64);
                s.y += __shfl_xor(s.y, 16, 64);
                s.z += __shfl_xor(s.z, 16, 64);
                s.w += __shfl_xor(s.w, 16, 64);
                s.x += __shfl_xor(s.x, 32, 64);
                s.y += __shfl_xor(s.y, 32, 64);
                s.z += __shfl_xor(s.z, 32, 64);
                s.w += __shfl_xor(s.w, 32, 64);
                float inv = 1.0f / (float)c;
                s.x *= inv; s.y *= inv; s.z *= inv; s.w *= inv;
                if (g == 0) ((float4*)sr)[sub] = s;
            }
        } else {
            // correctness-only path for pathological bucket overflow
            c = 0;
            float s0 = 0.f;
            for (int j0 = 0; j0 < cntb; j0 += 64) {
                int idx = j0 + lane;
                int p = (idx < cntb) ? binned[base + idx] : -1;
                bool m = (p >= 0) && ((p >> 21) == lid);
                unsigned long long msk = __ballot(m);
                c += __popcll(msk);
                while (msk) {
                    int l = __ffsll((long long)msk) - 1;
                    msk &= msk - 1;
                    int eid = __builtin_amdgcn_readlane(p, l) & 0x1FFFFF;
                    s0 += e[((size_t)eid << 6) + lane];
                }
            }
            if (c > 0) sr[lane] = s0 * (1.0f / (float)c);
        }

        // GEMV (common): 16 independent b128 broadcast reads from LDS
        float h0 = 0.0f, h1 = 0.0f;
        if (c > 0) {
            float aa0 = 0.f, aa1 = 0.f;
            const float4* sr4 = (const float4*)sr;
            #pragma unroll
            for (int q = 0; q < 16; q++) {
                float4 f = sr4[q];
                aa0 = fmaf(f.x, w0[4*q+0], aa0);  aa1 = fmaf(f.x, w1[4*q+0], aa1);
                aa0 = fmaf(f.y, w0[4*q+1], aa0);  aa1 = fmaf(f.y, w1[4*q+1], aa1);
                aa0 = fmaf(f.z, w0[4*q+2], aa0);  aa1 = fmaf(f.z, w1[4*q+2], aa1);
                aa0 = fmaf(f.w, w0[4*q+3], aa0);  aa1 = fmaf(f.w, w1[4*q+3], aa1);
            }
            h0 = aa0 + bb0;
            h1 = aa1 + bb1;
        }

        size_t ob2 = (size_t)node * OUT_F;
        out[ob2 + lane] = h0;
        if (lane < OUT_F - 64) out[ob2 + 64 + lane] = h1;
    }
}

// ===================== fallback path (atomic-based) =====================
__global__ void fb_hist(const int* __restrict__ dst, int* __restrict__ deg) {
    int i = (blockIdx.x * blockDim.x + threadIdx.x) * 4;
    if (i + 3 < N_EDGES) {
        int4 d = *(const int4*)(dst + i);
        atomicAdd(&deg[d.x], 1); atomicAdd(&deg[d.y], 1);
        atomicAdd(&deg[d.z], 1); atomicAdd(&deg[d.w], 1);
    } else {
        for (int k = i; k < N_EDGES; k++) atomicAdd(&deg[dst[k]], 1);
    }
}

__global__ void fb_scan(const int* __restrict__ deg, int* __restrict__ offs,
                        int* __restrict__ cursor, int* __restrict__ gcur) {
    int n = blockIdx.x * blockDim.x + threadIdx.x;
    int lane = threadIdx.x & 63;
    int d = (n < N_NODES) ? deg[n] : 0;
    int x = d;
    #pragma unroll
    for (int off = 1; off < 64; off <<= 1) {
        int y = __shfl_up(x, off, 64);
        if (lane >= off) x += y;
    }
    int excl = x - d;
    int total = __shfl(x, 63, 64);
    int bs = 0;
    if (lane == 63) bs = atomicAdd(gcur, total);
    bs = __shfl(bs, 63, 64);
    if (n < N_NODES) {
        offs[n] = bs + excl;
        cursor[n] = bs + excl;
    }
}

__global__ void fb_scatter(const int* __restrict__ dst, int* __restrict__ cursor,
                           int* __restrict__ eids) {
    int i = (blockIdx.x * blockDim.x + threadIdx.x) * 4;
    if (i + 3 < N_EDGES) {
        int4 d = *(const int4*)(dst + i);
        int p0 = atomicAdd(&cursor[d.x], 1);
        int p1 = atomicAdd(&cursor[d.y], 1);
        int p2 = atomicAdd(&cursor[d.z], 1);
        int p3 = atomicAdd(&cursor[d.w], 1);
        eids[p0] = i; eids[p1] = i + 1; eids[p2] = i + 2; eids[p3] = i + 3;
    } else {
        for (int k = i; k < N_EDGES; k++) {
            int pos = atomicAdd(&cursor[dst[k]], 1);
            eids[pos] = k;
        }
    }
}

__global__ void __launch_bounds__(256) fb_gather(
        const float* __restrict__ e, const int* __restrict__ eids,
        const int* __restrict__ offs, const int* __restrict__ deg,
        const float* __restrict__ W, const float* __restrict__ b,
        float* __restrict__ out, int n_waves_total) {
    __shared__ float srow[4][64];
    int lane = threadIdx.x & 63, w = (threadIdx.x >> 6) & 3;
    int wid  = (blockIdx.x * blockDim.x + threadIdx.x) >> 6;
    int row1 = 64 + lane;
    if (row1 >= OUT_F) row1 = 0;
    float w0[IN_F], w1[IN_F];
    const float4* W4 = (const float4*)W;
    #pragma unroll
    for (int j = 0; j < IN_F / 4; j++) {
        float4 t0 = W4[lane * (IN_F / 4) + j];
        w0[4*j+0] = t0.x; w0[4*j+1] = t0.y; w0[4*j+2] = t0.z; w0[4*j+3] = t0.w;
        float4 t1 = W4[row1 * (IN_F / 4) + j];
        w1[4*j+0] = t1.x; w1[4*j+1] = t1.y; w1[4*j+2] = t1.z; w1[4*j+3] = t1.w;
    }
    float bb0 = b[lane];
    float bb1 = b[row1];
    for (int n = wid; n < N_NODES; n += n_waves_total) {
        int o = __builtin_amdgcn_readfirstlane(offs[n]);
        int c = __builtin_amdgcn_readfirstlane(deg[n]);
        float s0 = 0.f, s1 = 0.f;
        for (int cb = 0; cb < c; cb += 64) {
            int cc = c - cb; if (cc > 64) cc = 64;
            int myeid = 0;
            if (lane < cc) myeid = eids[o + cb + lane];
            for (int j = 0; j < cc; j += 2) {
                int i0 = __builtin_amdgcn_readlane(myeid, j);
                s0 += e[((size_t)i0 << 6) + lane];
                if (j + 1 < cc) {
                    int i1 = __builtin_amdgcn_readlane(myeid, j + 1);
                    s1 += e[((size_t)i1 << 6) + lane];
                }
            }
        }
        float* sr = &srow[w][0];
        sr[lane] = (s0 + s1) * ((c > 0) ? 1.0f / (float)c : 0.0f);
        float a0 = 0.f, a1 = 0.f;
        const float4* sr4 = (const float4*)sr;
        #pragma unroll
        for (int q = 0; q < 16; q++) {
            float4 f = sr4[q];
            a0 = fmaf(f.x, w0[4*q+0], a0);  a1 = fmaf(f.x, w1[4*q+0], a1);
            a0 = fmaf(f.y, w0[4*q+1], a0);  a1 = fmaf(f.y, w1[4*q+1], a1);
            a0 = fmaf(f.z, w0[4*q+2], a0);  a1 = fmaf(f.z, w1[4*q+2], a1);
            a0 = fmaf(f.w, w0[4*q+3], a0);  a1 = fmaf(f.w, w1[4*q+3], a1);
        }
        float h0 = (c > 0) ? a0 + bb0 : 0.0f;
        float h1 = (c > 0) ? a1 + bb1 : 0.0f;
        size_t ob = (size_t)n * OUT_F;
        out[ob + lane] = h0;
        if (lane < OUT_F - 64) out[ob + 64 + lane] = h1;
    }
}

extern "C" void kernel_launch(void* const* d_in, const int* in_sizes, int n_in,
                              void* d_out, int out_size, void* d_ws, size_t ws_size,
                              hipStream_t stream) {
    const float* e   = (const float*)d_in[0];
    const int*   dst = (const int*)d_in[1];
    const float* W   = (const float*)d_in[2];
    const float* b   = (const float*)d_in[3];
    float* out = (float*)d_out;
    char* ws = (char*)d_ws;

    if (ws_size >= (size_t)WS_NEEDED) {
        int* cnt    = (int*)(ws + OFF_CNT);
        int* part   = (int*)(ws + OFF_PART);
        int* binned = (int*)(ws + OFF_BIN);

        k_count<<<NBLK, 256, 0, stream>>>(dst, cnt);
        k_s1   <<<SB, 256, 0, stream>>>(cnt, part);
        k_s2   <<<1, 64, 0, stream>>>(part);
        k_s3   <<<SB, 256, 0, stream>>>(cnt, part);
        k_bin  <<<NBLK, 256, 0, stream>>>(dst, cnt, binned);
        k_fused<<<K_BUCKETS, 256, 0, stream>>>(e, binned, cnt, W, b, out);
    } else {
        int* deg    = (int*)(ws + FB_DEG);
        int* offs   = (int*)(ws + FB_OFFS);
        int* cursor = (int*)(ws + FB_CURSOR);
        int* gcur   = (int*)(ws + FB_GCUR);
        int* eids   = (int*)(ws + FB_EIDS);

        hipMemsetAsync(deg, 0, N_NODES * sizeof(int), stream);
        hipMemsetAsync(gcur, 0, sizeof(int), stream);
        fb_hist   <<<(N_EDGES / 4 + 255) / 256, 256, 0, stream>>>(dst, deg);
        fb_scan   <<<(N_NODES + 255) / 256, 256, 0, stream>>>(deg, offs, cursor, gcur);
        fb_scatter<<<(N_EDGES / 4 + 255) / 256, 256, 0, stream>>>(dst, cursor, eids);
        fb_gather <<<8192, 256, 0, stream>>>(e, eids, offs, deg, W, b, out, 8192 * 4);
    }
}